// Round 8
// baseline (474.079 us; speedup 1.0000x reference)
//
#include <hip/hip_runtime.h>
#include <hip/hip_bf16.h>
#include <hip/hip_fp16.h>
#include <math.h>

constexpr int NN = 100000;
constexpr int EE = 1000000;
constexpr int RRR = 3;
constexpr int DIN = 128;
constexpr int DOUT = 64;
constexpr float SLOPE = 0.2f;
constexpr int NR = RRR * NN;                    // 300000 segments (relation-major)
constexpr int BSEG = 256;                       // segments per bucket
constexpr int NBUCK = (NR + BSEG - 1) / BSEG;   // 1172
constexpr int BCAP = 4096;                      // max edges/bucket (mean 2560, sigma ~51)
constexpr int CHUNK_E = 8192;                   // edges per chunk-block
constexpr int NCH_PER_R = (EE + CHUNK_E - 1) / CHUNK_E;   // 123
constexpr int NCH = RRR * NCH_PER_R;            // 369
constexpr int MT = NBUCK * NCH;                 // 432468 matrix entries
constexpr int SCAN_CHUNK = 1024;
constexpr int NSCB = (MT + SCAN_CHUNK - 1) / SCAN_CHUNK;  // 423

// ---------------- W pre-transpose: Wt[r][c][k] = W[r][k][c] ----------------
__global__ __launch_bounds__(256) void transpose_W(
    const float* __restrict__ W1, const float* __restrict__ W2,
    float* __restrict__ Wt1, float* __restrict__ Wt2)
{
    int m = blockIdx.x;     // 0..2: W1 (K=128), 3..5: W2 (K=64)
    int t = threadIdx.x;
    if (m < 3) {
        const float* src = W1 + (size_t)m * DIN * DOUT;
        float* dst = Wt1 + (size_t)m * DIN * DOUT;
        for (int i = t; i < DIN * DOUT; i += 256) {
            int k = i >> 6, c = i & 63;
            dst[c * DIN + k] = src[i];
        }
    } else {
        const float* src = W2 + (size_t)(m - 3) * DOUT * DOUT;
        float* dst = Wt2 + (size_t)(m - 3) * DOUT * DOUT;
        for (int i = t; i < DOUT * DOUT; i += 256) {
            int k = i >> 6, c = i & 63;
            dst[c * DOUT + k] = src[i];
        }
    }
}

// ---------------- GEMM + attention logits v4: lane=row, x direct-from-global, no k-loop LDS ----------------
// block: 256 thr = 4 waves; 64 rows (lane=row) x 64 cols (wave owns 16 cols).
// x read per-lane (stride 512B; 64B line covers 4 k4-iters -> L1-resident).
// W read wave-uniform -> s_load; LDS only for output staging (18.7KB -> 8 blocks/CU).
template<int INP>
__global__ __launch_bounds__(256) void gemm_att4(
    const float* __restrict__ x,     // [NN, INP]
    const float* __restrict__ Wt,    // [R, 64, INP] (k-contiguous per col)
    const float* __restrict__ asrc,  // [R, 64]
    const float* __restrict__ adst,  // [R, 64]
    __half* __restrict__ h,          // [R, NN, 64] fp16
    float* __restrict__ als,         // [R, NN]
    float* __restrict__ ald)         // [R, NN]
{
    __shared__ float outb[64 * 65];             // output staging (stride 65: conflict-free scalar)
    __shared__ float parts[512];                // als/ald partials: [2][4][64]
    const int t = threadIdx.x;
    const int lane = t & 63;
    const int warp_s = __builtin_amdgcn_readfirstlane(t >> 6);
    const int r = blockIdx.y;
    const int row0 = blockIdx.x * 64;

    int grow = row0 + lane; if (grow >= NN) grow = NN - 1;   // tail clamp
    const float* xrow = x + (size_t)grow * INP;
    const float* wbase = Wt + ((size_t)r * 64 + warp_s * 16) * INP;

    float acc[16];
#pragma unroll
    for (int i = 0; i < 16; ++i) acc[i] = 0.f;

#pragma unroll 2
    for (int k4 = 0; k4 < INP / 4; ++k4) {
        float4 xv = *(const float4*)(xrow + k4 * 4);         // per-lane, L1-hit 3/4 iters
#pragma unroll
        for (int i = 0; i < 16; ++i) {
            float4 wv = *(const float4*)(wbase + i * INP + k4 * 4);  // wave-uniform -> s_load
            acc[i] = fmaf(xv.x, wv.x, acc[i]);
            acc[i] = fmaf(xv.y, wv.y, acc[i]);
            acc[i] = fmaf(xv.z, wv.z, acc[i]);
            acc[i] = fmaf(xv.w, wv.w, acc[i]);
        }
    }

    // als/ald partials from registers (cols warp_s*16..+15)
    {
        const float* av = asrc + r * 64 + warp_s * 16;
        const float* dv = adst + r * 64 + warp_s * 16;
        float ps = 0.f, pd = 0.f;
#pragma unroll
        for (int i = 0; i < 16; ++i) { ps = fmaf(acc[i], av[i], ps); pd = fmaf(acc[i], dv[i], pd); }
        parts[warp_s * 64 + lane] = ps;
        parts[256 + warp_s * 64 + lane] = pd;
    }

#pragma unroll
    for (int i = 0; i < 16; ++i) outb[lane * 65 + warp_s * 16 + i] = acc[i];
    __syncthreads();

    const int nrows = (NN - row0 < 64) ? (NN - row0) : 64;
    __half2* h2 = (__half2*)(h + ((size_t)r * NN + row0) * 64);
    for (int idx = t; idx < nrows * 32; idx += 256) {
        int row = idx >> 5, cc = idx & 31;
        float f0 = outb[row * 65 + cc * 2];
        float f1 = outb[row * 65 + cc * 2 + 1];
        h2[row * 32 + cc] = __floats2half2_rn(f0, f1);    // coalesced 4B stores
    }
    if (t < nrows) {
        float s = parts[t] + parts[64 + t] + parts[128 + t] + parts[192 + t];
        float d = parts[256 + t] + parts[320 + t] + parts[384 + t] + parts[448 + t];
        als[r * NN + row0 + t] = s;
        ald[r * NN + row0 + t] = d;
    }
}

// ---------------- CSR build: deterministic counting-sort, NO global atomics ----------------

__global__ __launch_bounds__(256) void chunk_hist(
    const int* __restrict__ ei0, const int* __restrict__ ei1, const int* __restrict__ ei2,
    unsigned* __restrict__ M)
{
    __shared__ unsigned hist[NBUCK];
    const int r = blockIdx.y, bx = blockIdx.x;
    const int* ei = (r == 0) ? ei0 : ((r == 1) ? ei1 : ei2);
    const int t = threadIdx.x;
    for (int i = t; i < NBUCK; i += 256) hist[i] = 0;
    __syncthreads();
    const int e0 = bx * CHUNK_E;
    const int e1 = (e0 + CHUNK_E < EE) ? e0 + CHUNK_E : EE;
    for (int e = e0 + t; e < e1; e += 256) {
        int idx = r * NN + ei[EE + e];
        atomicAdd(&hist[idx >> 8], 1u);
    }
    __syncthreads();
    const int c = r * NCH_PER_R + bx;
    for (int i = t; i < NBUCK; i += 256) M[(size_t)i * NCH + c] = hist[i];
}

__global__ __launch_bounds__(256) void scan_block(unsigned* __restrict__ data, unsigned* __restrict__ bsum)
{
    __shared__ unsigned tsum[256];
    const int base = blockIdx.x * SCAN_CHUNK;
    const int t = threadIdx.x;
    const int i0 = base + t * 4;
    unsigned v[4];
#pragma unroll
    for (int k = 0; k < 4; ++k) v[k] = (i0 + k < MT) ? data[i0 + k] : 0u;
    unsigned run = 0;
#pragma unroll
    for (int k = 0; k < 4; ++k) { unsigned x = v[k]; v[k] = run; run += x; }
    tsum[t] = run;
    __syncthreads();
    unsigned val = run;
    for (int d = 1; d < 256; d <<= 1) {
        unsigned add = (t >= d) ? tsum[t - d] : 0u;
        __syncthreads();
        val += add;
        tsum[t] = val;
        __syncthreads();
    }
    unsigned texcl = val - run;
    if (t == 255) bsum[blockIdx.x] = val;
#pragma unroll
    for (int k = 0; k < 4; ++k)
        if (i0 + k < MT) data[i0 + k] = texcl + v[k];
}

__global__ __launch_bounds__(256) void scan_bsums(unsigned* __restrict__ bsum)
{
    __shared__ unsigned s[NSCB];
    int t = threadIdx.x;
    for (int i = t; i < NSCB; i += 256) s[i] = bsum[i];
    __syncthreads();
    if (t == 0) {
        unsigned run = 0;
        for (int i = 0; i < NSCB; ++i) { unsigned x = s[i]; s[i] = run; run += x; }
    }
    __syncthreads();
    for (int i = t; i < NSCB; i += 256) bsum[i] = s[i];
}

__global__ __launch_bounds__(256) void add_off(unsigned* __restrict__ data, const unsigned* __restrict__ bsum)
{
    int i = blockIdx.x * 256 + threadIdx.x;
    if (i >= MT) return;
    data[i] += bsum[i / SCAN_CHUNK];
}

__global__ __launch_bounds__(256) void chunk_scatter(
    const int* __restrict__ ei0, const int* __restrict__ ei1, const int* __restrict__ ei2,
    const unsigned* __restrict__ Ms, unsigned* __restrict__ packed)
{
    __shared__ unsigned cur[NBUCK];
    const int r = blockIdx.y, bx = blockIdx.x;
    const int* ei = (r == 0) ? ei0 : ((r == 1) ? ei1 : ei2);
    const int t = threadIdx.x;
    const int c = r * NCH_PER_R + bx;
    for (int i = t; i < NBUCK; i += 256) cur[i] = Ms[(size_t)i * NCH + c];
    __syncthreads();
    const int e0 = bx * CHUNK_E;
    const int e1 = (e0 + CHUNK_E < EE) ? e0 + CHUNK_E : EE;
    for (int e = e0 + t; e < e1; e += 256) {
        int src = ei[e];
        int idx = r * NN + ei[EE + e];
        unsigned pos = atomicAdd(&cur[idx >> 8], 1u);
        packed[pos] = (unsigned)src | ((unsigned)(idx & 255) << 24);
    }
}

__global__ __launch_bounds__(256) void bucket_build(
    unsigned* __restrict__ packed,        // in: pairs; out: csr_src (same buffer)
    const unsigned* __restrict__ Ms,      // scanned matrix: Ms[b*NCH] = bucket base
    unsigned* __restrict__ off)           // [NR]
{
    __shared__ unsigned sp[BCAP];
    __shared__ unsigned ssrc[BCAP];
    __shared__ unsigned scnt[BSEG];
    __shared__ unsigned scur[BSEG];
    __shared__ unsigned tsum[BSEG];
    const int b = blockIdx.x;
    const int t = threadIdx.x;
    const unsigned base = Ms[(size_t)b * NCH];
    const unsigned next = (b + 1 < NBUCK) ? Ms[(size_t)(b + 1) * NCH] : (unsigned)((size_t)RRR * EE);
    int cnt = (int)(next - base);
    if (cnt > BCAP) cnt = BCAP;
    for (int i = t; i < cnt; i += 256) sp[i] = packed[base + i];
    scnt[t] = 0;
    __syncthreads();
    for (int i = t; i < cnt; i += 256) atomicAdd(&scnt[sp[i] >> 24], 1u);
    __syncthreads();
    unsigned v = scnt[t];
    tsum[t] = v;
    __syncthreads();
    unsigned val = v;
    for (int d = 1; d < 256; d <<= 1) {
        unsigned add = (t >= d) ? tsum[t - d] : 0u;
        __syncthreads();
        val += add;
        tsum[t] = val;
        __syncthreads();
    }
    unsigned excl = val - v;
    scur[t] = excl;
    const int segs = (NR - b * BSEG < BSEG) ? (NR - b * BSEG) : BSEG;
    if (t < segs) off[b * BSEG + t] = base + excl;
    __syncthreads();
    for (int i = t; i < cnt; i += 256) {
        unsigned p = sp[i];
        unsigned pos = atomicAdd(&scur[p >> 24], 1u);
        ssrc[pos] = p & 0x00FFFFFFu;
    }
    __syncthreads();
    for (int i = t; i < cnt; i += 256) packed[base + i] = ssrc[i];
}

// ---------------- aggregation v5: single-tile softmax + fp16 gather with inactive-half skip ----------------
template<bool L1>
__global__ __launch_bounds__(256) void aggregate5(
    const int* __restrict__ csr_src, const unsigned* __restrict__ off,
    const __half* __restrict__ h,    // [R, NN, 64] fp16
    const float* __restrict__ als, const float* __restrict__ ald,  // [R, NN]
    const float* __restrict__ bias,  // [R, 64]
    float* __restrict__ outp)        // [NN, 64]
{
    __shared__ float sbuf[4][64];    // fallback-path layout conversion only
    const int wid = threadIdx.x >> 6;
    const int node = blockIdx.x * 4 + wid;
    if (node >= NN) return;
    const int lane = threadIdx.x & 63;
    const int sub = lane >> 4;       // edge-in-group 0..3
    const int fc = lane & 15;        // feature chunk 0..15 (4 features each)

    unsigned start[RRR]; int cnt[RRR]; float aldv[RRR];
    int maxcnt = 0;
#pragma unroll
    for (int r = 0; r < RRR; ++r) {
        int idx = r * NN + node;
        unsigned s = off[idx];
        unsigned e = (idx == NR - 1) ? (unsigned)((size_t)RRR * EE) : off[idx + 1];
        start[r] = s; cnt[r] = (int)(e - s); aldv[r] = ald[idx];
        if (cnt[r] > maxcnt) maxcnt = cnt[r];
    }

    float4 total = make_float4(0.f, 0.f, 0.f, 0.f);

    if (maxcnt <= 64) {
        // ---- fused single-tile path (max degree << 64 for this data) ----
        int srcv[RRR]; float lr[RRR];
#pragma unroll
        for (int r = 0; r < RRR; ++r) {
            bool act = lane < cnt[r];
            int s_ = act ? csr_src[start[r] + lane] : 0;      // coalesced
            srcv[r] = s_;
            float sv = act ? (als[r * NN + s_] + aldv[r]) : -3.0e38f;  // 4B gather, L2-resident
            lr[r] = (sv > 0.f) ? sv : SLOPE * sv;
        }
        float m[RRR];
#pragma unroll
        for (int r = 0; r < RRR; ++r) m[r] = lr[r];
#pragma unroll
        for (int o = 32; o; o >>= 1) {
#pragma unroll
            for (int r = 0; r < RRR; ++r) m[r] = fmaxf(m[r], __shfl_xor(m[r], o));
        }
        float p[RRR], den[RRR];
#pragma unroll
        for (int r = 0; r < RRR; ++r) {
            p[r] = (lane < cnt[r]) ? __expf(lr[r] - m[r]) : 0.f;
            den[r] = p[r];
        }
#pragma unroll
        for (int o = 32; o; o >>= 1) {
#pragma unroll
            for (int r = 0; r < RRR; ++r) den[r] += __shfl_xor(den[r], o);
        }
#pragma unroll
        for (int r = 0; r < RRR; ++r) {
            float inv = (cnt[r] > 0) ? 1.f / den[r] : 0.f;
            const __half* hr = h + (size_t)r * NN * DOUT;
            float4 acc = make_float4(0.f, 0.f, 0.f, 0.f);
            const int ng = (cnt[r] + 3) >> 2;
            for (int g = 0; g < ng; g += 2) {
                int ea = g * 4 + sub;
                float pa = __shfl(p[r], ea);
                int sa = __shfl(srcv[r], ea);
                uint2 ra = *(const uint2*)(hr + (size_t)sa * DOUT + fc * 4);  // 8B = 4 halves
                float2 fa01 = __half22float2(*(const __half2*)&ra.x);
                float2 fa23 = __half22float2(*(const __half2*)&ra.y);
                acc.x = fmaf(pa, fa01.x, acc.x);
                acc.y = fmaf(pa, fa01.y, acc.y);
                acc.z = fmaf(pa, fa23.x, acc.z);
                acc.w = fmaf(pa, fa23.y, acc.w);
                if ((g + 1) * 4 < cnt[r]) {       // wave-uniform: skip all-inactive half
                    int eb = ea + 4;
                    float pb = __shfl(p[r], eb);
                    int sb = __shfl(srcv[r], eb);
                    uint2 rb = *(const uint2*)(hr + (size_t)sb * DOUT + fc * 4);
                    float2 fb01 = __half22float2(*(const __half2*)&rb.x);
                    float2 fb23 = __half22float2(*(const __half2*)&rb.y);
                    acc.x = fmaf(pb, fb01.x, acc.x);
                    acc.y = fmaf(pb, fb01.y, acc.y);
                    acc.z = fmaf(pb, fb23.x, acc.z);
                    acc.w = fmaf(pb, fb23.y, acc.w);
                }
            }
            // reduce over the 4 sub-groups
            acc.x += __shfl_xor(acc.x, 16); acc.y += __shfl_xor(acc.y, 16);
            acc.z += __shfl_xor(acc.z, 16); acc.w += __shfl_xor(acc.w, 16);
            acc.x += __shfl_xor(acc.x, 32); acc.y += __shfl_xor(acc.y, 32);
            acc.z += __shfl_xor(acc.z, 32); acc.w += __shfl_xor(acc.w, 32);
            total.x = fmaf(acc.x, inv, total.x);
            total.y = fmaf(acc.y, inv, total.y);
            total.z = fmaf(acc.z, inv, total.z);
            total.w = fmaf(acc.w, inv, total.w);
        }
    } else {
        // ---- general fallback: online softmax, scalar broadcast (lane=feature) ----
        float totalS = 0.f;
#pragma unroll
        for (int r = 0; r < RRR; ++r) {
            if (cnt[r] <= 0) continue;
            const __half* hr = h + (size_t)r * NN * DOUT;
            const float* alsr = als + (size_t)r * NN;
            float m = -3.4e38f, den = 0.f, accv = 0.f;
            for (int t0 = 0; t0 < cnt[r]; t0 += 64) {
                int j = t0 + lane;
                bool act = (j < cnt[r]);
                int src = 0;
                float lrv = -3.4e38f;
                if (act) {
                    src = csr_src[start[r] + j];
                    float sv = alsr[src] + aldv[r];
                    lrv = (sv > 0.f) ? sv : SLOPE * sv;
                }
                float mt = lrv;
#pragma unroll
                for (int o = 32; o; o >>= 1) mt = fmaxf(mt, __shfl_xor(mt, o));
                float mnew = fmaxf(m, mt);
                float scale = __expf(m - mnew);
                den *= scale; accv *= scale; m = mnew;
                float p = act ? __expf(lrv - m) : 0.f;
                float ps = p;
#pragma unroll
                for (int o = 32; o; o >>= 1) ps += __shfl_xor(ps, o);
                den += ps;
                int tcnt = cnt[r] - t0; if (tcnt > 64) tcnt = 64;
                for (int j2 = 0; j2 < tcnt; ++j2) {
                    int sj = __builtin_amdgcn_readlane(src, j2);
                    float pj = __int_as_float(__builtin_amdgcn_readlane(__float_as_int(p), j2));
                    accv = fmaf(pj, __half2float(hr[(size_t)sj * DOUT + lane]), accv);
                }
            }
            totalS += accv / den;
        }
        sbuf[wid][lane] = totalS;     // wave-internal layout conversion
        __builtin_amdgcn_s_waitcnt(0);
        total = *(const float4*)&sbuf[wid][fc * 4];
    }

    // ---- epilogue in float4 layout (replicated across sub) ----
    float4 b4 = make_float4(0.f, 0.f, 0.f, 0.f);
#pragma unroll
    for (int r = 0; r < RRR; ++r) {
        float4 bb = *(const float4*)(bias + r * DOUT + fc * 4);
        b4.x += bb.x; b4.y += bb.y; b4.z += bb.z; b4.w += bb.w;
    }
    float4 v;
    v.x = (total.x + b4.x) * (1.f / 3.f);
    v.y = (total.y + b4.y) * (1.f / 3.f);
    v.z = (total.z + b4.z) * (1.f / 3.f);
    v.w = (total.w + b4.w) * (1.f / 3.f);
    if (L1) {
        float ss = v.x * v.x + v.y * v.y + v.z * v.z + v.w * v.w;
#pragma unroll
        for (int o = 8; o; o >>= 1) ss += __shfl_xor(ss, o);   // sum over 16 fc in sub-group
        float di = 1.f / fmaxf(sqrtf(ss), 1e-12f);
        v.x = fmaxf(v.x * di, 0.f);
        v.y = fmaxf(v.y * di, 0.f);
        v.z = fmaxf(v.z * di, 0.f);
        v.w = fmaxf(v.w * di, 0.f);
    }
    if (sub == 0) *(float4*)(outp + (size_t)node * DOUT + fc * 4) = v;  // 256B/node, coalesced
}

// ---------------- launch ----------------
extern "C" void kernel_launch(void* const* d_in, const int* in_sizes, int n_in,
                              void* d_out, int out_size, void* d_ws, size_t ws_size,
                              hipStream_t stream) {
    const float* x   = (const float*)d_in[0];
    const int* ei0   = (const int*)d_in[1];
    const int* ei1   = (const int*)d_in[2];
    const int* ei2   = (const int*)d_in[3];
    const float* W1  = (const float*)d_in[4];
    const float* as1 = (const float*)d_in[5];
    const float* ad1 = (const float*)d_in[6];
    const float* b1  = (const float*)d_in[7];
    const float* W2  = (const float*)d_in[8];
    const float* as2 = (const float*)d_in[9];
    const float* ad2 = (const float*)d_in[10];
    const float* b2  = (const float*)d_in[11];
    float* out = (float*)d_out;

    // workspace carve-up (4B units)
    float* ws = (float*)d_ws;
    size_t off_u = 0;
    __half* h       = (__half*)(ws + off_u); off_u += (size_t)RRR * NN * DOUT / 2;  // fp16: 9.6M floats
    float* als      = ws + off_u; off_u += (size_t)RRR * NN;
    float* ald      = ws + off_u; off_u += (size_t)RRR * NN;
    unsigned* packed= (unsigned*)(ws + off_u); off_u += (size_t)RRR * EE; // 3M; becomes csr_src
    unsigned* off   = (unsigned*)(ws + off_u); off_u += NR;
    float* Wt1      = ws + off_u; off_u += (size_t)RRR * DIN * DOUT;
    float* Wt2      = ws + off_u; off_u += (size_t)RRR * DOUT * DOUT;
    float* hmid     = ws + off_u;                                          // 6.4M floats
    unsigned* M     = (unsigned*)hmid;          // overlaps hmid: MT=432k < 6.4M; dead before layer 1
    unsigned* bsum  = M + MT;

    dim3 blk(256);
    dim3 gG2((NN + 63) / 64, RRR);    // 1563 x 3
    dim3 gC(NCH_PER_R, RRR);          // 123 x 3
    int gA = NN / 4;                  // 25000

    // ---- CSR build (deterministic, no global atomics; shared by both layers) ----
    chunk_hist<<<gC, blk, 0, stream>>>(ei0, ei1, ei2, M);
    scan_block<<<NSCB, blk, 0, stream>>>(M, bsum);
    scan_bsums<<<1, blk, 0, stream>>>(bsum);
    add_off<<<(MT + 255) / 256, blk, 0, stream>>>(M, bsum);
    chunk_scatter<<<gC, blk, 0, stream>>>(ei0, ei1, ei2, M, packed);
    bucket_build<<<NBUCK, blk, 0, stream>>>(packed, M, off);
    const int* csr_src = (const int*)packed;

    transpose_W<<<6, blk, 0, stream>>>(W1, W2, Wt1, Wt2);

    // ---- layer 1 ----
    gemm_att4<DIN><<<gG2, blk, 0, stream>>>(x, Wt1, as1, ad1, h, als, ald);
    aggregate5<true><<<gA, blk, 0, stream>>>(csr_src, off, h, als, ald, b1, hmid);

    // ---- layer 2 ----
    gemm_att4<DOUT><<<gG2, blk, 0, stream>>>(hmid, Wt2, as2, ad2, h, als, ald);
    aggregate5<false><<<gA, blk, 0, stream>>>(csr_src, off, h, als, ald, b2, out);
}

// Round 9
// 441.693 us; speedup vs baseline: 1.0733x; 1.0733x over previous
//
#include <hip/hip_runtime.h>
#include <hip/hip_bf16.h>
#include <hip/hip_fp16.h>
#include <math.h>

constexpr int NN = 100000;
constexpr int EE = 1000000;
constexpr int RRR = 3;
constexpr int DIN = 128;
constexpr int DOUT = 64;
constexpr float SLOPE = 0.2f;
constexpr int NR = RRR * NN;                    // 300000 segments (relation-major)
constexpr int BSEG = 256;                       // segments per bucket
constexpr int NBUCK = (NR + BSEG - 1) / BSEG;   // 1172
constexpr int BCAP = 4096;                      // max edges/bucket (mean 2560, sigma ~51)
constexpr int CHUNK_E = 8192;                   // edges per chunk-block
constexpr int NCH_PER_R = (EE + CHUNK_E - 1) / CHUNK_E;   // 123
constexpr int NCH = RRR * NCH_PER_R;            // 369
constexpr int MT = NBUCK * NCH;                 // 432468 matrix entries
constexpr int SCAN_CHUNK = 1024;
constexpr int NSCB = (MT + SCAN_CHUNK - 1) / SCAN_CHUNK;  // 423

// ---------------- W pre-transpose: Wt[r][c][k] = W[r][k][c] ----------------
__global__ __launch_bounds__(256) void transpose_W(
    const float* __restrict__ W1, const float* __restrict__ W2,
    float* __restrict__ Wt1, float* __restrict__ Wt2)
{
    int m = blockIdx.x;     // 0..2: W1 (K=128), 3..5: W2 (K=64)
    int t = threadIdx.x;
    if (m < 3) {
        const float* src = W1 + (size_t)m * DIN * DOUT;
        float* dst = Wt1 + (size_t)m * DIN * DOUT;
        for (int i = t; i < DIN * DOUT; i += 256) {
            int k = i >> 6, c = i & 63;
            dst[c * DIN + k] = src[i];
        }
    } else {
        const float* src = W2 + (size_t)(m - 3) * DOUT * DOUT;
        float* dst = Wt2 + (size_t)(m - 3) * DOUT * DOUT;
        for (int i = t; i < DOUT * DOUT; i += 256) {
            int k = i >> 6, c = i & 63;
            dst[c * DOUT + k] = src[i];
        }
    }
}

// ---------------- GEMM + attention logits v4: lane=row, x direct-from-global, no k-loop LDS ----------------
template<int INP>
__global__ __launch_bounds__(256) void gemm_att4(
    const float* __restrict__ x,     // [NN, INP]
    const float* __restrict__ Wt,    // [R, 64, INP] (k-contiguous per col)
    const float* __restrict__ asrc,  // [R, 64]
    const float* __restrict__ adst,  // [R, 64]
    __half* __restrict__ h,          // [R, NN, 64] fp16
    float* __restrict__ als,         // [R, NN]
    float* __restrict__ ald)         // [R, NN]
{
    __shared__ float outb[64 * 65];             // output staging (stride 65: conflict-free scalar)
    __shared__ float parts[512];                // als/ald partials: [2][4][64]
    const int t = threadIdx.x;
    const int lane = t & 63;
    const int warp_s = __builtin_amdgcn_readfirstlane(t >> 6);
    const int r = blockIdx.y;
    const int row0 = blockIdx.x * 64;

    int grow = row0 + lane; if (grow >= NN) grow = NN - 1;   // tail clamp
    const float* xrow = x + (size_t)grow * INP;
    const float* wbase = Wt + ((size_t)r * 64 + warp_s * 16) * INP;

    float acc[16];
#pragma unroll
    for (int i = 0; i < 16; ++i) acc[i] = 0.f;

#pragma unroll 2
    for (int k4 = 0; k4 < INP / 4; ++k4) {
        float4 xv = *(const float4*)(xrow + k4 * 4);         // per-lane, L1-hit 3/4 iters
#pragma unroll
        for (int i = 0; i < 16; ++i) {
            float4 wv = *(const float4*)(wbase + i * INP + k4 * 4);  // wave-uniform -> s_load
            acc[i] = fmaf(xv.x, wv.x, acc[i]);
            acc[i] = fmaf(xv.y, wv.y, acc[i]);
            acc[i] = fmaf(xv.z, wv.z, acc[i]);
            acc[i] = fmaf(xv.w, wv.w, acc[i]);
        }
    }

    // als/ald partials from registers (cols warp_s*16..+15)
    {
        const float* av = asrc + r * 64 + warp_s * 16;
        const float* dv = adst + r * 64 + warp_s * 16;
        float ps = 0.f, pd = 0.f;
#pragma unroll
        for (int i = 0; i < 16; ++i) { ps = fmaf(acc[i], av[i], ps); pd = fmaf(acc[i], dv[i], pd); }
        parts[warp_s * 64 + lane] = ps;
        parts[256 + warp_s * 64 + lane] = pd;
    }

#pragma unroll
    for (int i = 0; i < 16; ++i) outb[lane * 65 + warp_s * 16 + i] = acc[i];
    __syncthreads();

    const int nrows = (NN - row0 < 64) ? (NN - row0) : 64;
    __half2* h2 = (__half2*)(h + ((size_t)r * NN + row0) * 64);
    for (int idx = t; idx < nrows * 32; idx += 256) {
        int row = idx >> 5, cc = idx & 31;
        float f0 = outb[row * 65 + cc * 2];
        float f1 = outb[row * 65 + cc * 2 + 1];
        h2[row * 32 + cc] = __floats2half2_rn(f0, f1);    // coalesced 4B stores
    }
    if (t < nrows) {
        float s = parts[t] + parts[64 + t] + parts[128 + t] + parts[192 + t];
        float d = parts[256 + t] + parts[320 + t] + parts[384 + t] + parts[448 + t];
        als[r * NN + row0 + t] = s;
        ald[r * NN + row0 + t] = d;
    }
}

// ---------------- CSR build: deterministic counting-sort, NO global atomics ----------------

__global__ __launch_bounds__(256) void chunk_hist(
    const int* __restrict__ ei0, const int* __restrict__ ei1, const int* __restrict__ ei2,
    unsigned* __restrict__ M)
{
    __shared__ unsigned hist[NBUCK];
    const int r = blockIdx.y, bx = blockIdx.x;
    const int* ei = (r == 0) ? ei0 : ((r == 1) ? ei1 : ei2);
    const int t = threadIdx.x;
    for (int i = t; i < NBUCK; i += 256) hist[i] = 0;
    __syncthreads();
    const int e0 = bx * CHUNK_E;
    const int e1 = (e0 + CHUNK_E < EE) ? e0 + CHUNK_E : EE;
    for (int e = e0 + t; e < e1; e += 256) {
        int idx = r * NN + ei[EE + e];
        atomicAdd(&hist[idx >> 8], 1u);
    }
    __syncthreads();
    const int c = r * NCH_PER_R + bx;
    for (int i = t; i < NBUCK; i += 256) M[(size_t)i * NCH + c] = hist[i];
}

__global__ __launch_bounds__(256) void scan_block(unsigned* __restrict__ data, unsigned* __restrict__ bsum)
{
    __shared__ unsigned tsum[256];
    const int base = blockIdx.x * SCAN_CHUNK;
    const int t = threadIdx.x;
    const int i0 = base + t * 4;
    unsigned v[4];
#pragma unroll
    for (int k = 0; k < 4; ++k) v[k] = (i0 + k < MT) ? data[i0 + k] : 0u;
    unsigned run = 0;
#pragma unroll
    for (int k = 0; k < 4; ++k) { unsigned x = v[k]; v[k] = run; run += x; }
    tsum[t] = run;
    __syncthreads();
    unsigned val = run;
    for (int d = 1; d < 256; d <<= 1) {
        unsigned add = (t >= d) ? tsum[t - d] : 0u;
        __syncthreads();
        val += add;
        tsum[t] = val;
        __syncthreads();
    }
    unsigned texcl = val - run;
    if (t == 255) bsum[blockIdx.x] = val;
#pragma unroll
    for (int k = 0; k < 4; ++k)
        if (i0 + k < MT) data[i0 + k] = texcl + v[k];
}

__global__ __launch_bounds__(256) void scan_bsums(unsigned* __restrict__ bsum)
{
    __shared__ unsigned s[NSCB];
    int t = threadIdx.x;
    for (int i = t; i < NSCB; i += 256) s[i] = bsum[i];
    __syncthreads();
    if (t == 0) {
        unsigned run = 0;
        for (int i = 0; i < NSCB; ++i) { unsigned x = s[i]; s[i] = run; run += x; }
    }
    __syncthreads();
    for (int i = t; i < NSCB; i += 256) bsum[i] = s[i];
}

__global__ __launch_bounds__(256) void add_off(unsigned* __restrict__ data, const unsigned* __restrict__ bsum)
{
    int i = blockIdx.x * 256 + threadIdx.x;
    if (i >= MT) return;
    data[i] += bsum[i / SCAN_CHUNK];
}

__global__ __launch_bounds__(256) void chunk_scatter(
    const int* __restrict__ ei0, const int* __restrict__ ei1, const int* __restrict__ ei2,
    const unsigned* __restrict__ Ms, unsigned* __restrict__ packed)
{
    __shared__ unsigned cur[NBUCK];
    const int r = blockIdx.y, bx = blockIdx.x;
    const int* ei = (r == 0) ? ei0 : ((r == 1) ? ei1 : ei2);
    const int t = threadIdx.x;
    const int c = r * NCH_PER_R + bx;
    for (int i = t; i < NBUCK; i += 256) cur[i] = Ms[(size_t)i * NCH + c];
    __syncthreads();
    const int e0 = bx * CHUNK_E;
    const int e1 = (e0 + CHUNK_E < EE) ? e0 + CHUNK_E : EE;
    for (int e = e0 + t; e < e1; e += 256) {
        int src = ei[e];
        int idx = r * NN + ei[EE + e];
        unsigned pos = atomicAdd(&cur[idx >> 8], 1u);
        packed[pos] = (unsigned)src | ((unsigned)(idx & 255) << 24);
    }
}

__global__ __launch_bounds__(256) void bucket_build(
    unsigned* __restrict__ packed,        // in: pairs; out: csr_src (same buffer)
    const unsigned* __restrict__ Ms,      // scanned matrix: Ms[b*NCH] = bucket base
    unsigned* __restrict__ off)           // [NR]
{
    __shared__ unsigned sp[BCAP];
    __shared__ unsigned ssrc[BCAP];
    __shared__ unsigned scnt[BSEG];
    __shared__ unsigned scur[BSEG];
    __shared__ unsigned tsum[BSEG];
    const int b = blockIdx.x;
    const int t = threadIdx.x;
    const unsigned base = Ms[(size_t)b * NCH];
    const unsigned next = (b + 1 < NBUCK) ? Ms[(size_t)(b + 1) * NCH] : (unsigned)((size_t)RRR * EE);
    int cnt = (int)(next - base);
    if (cnt > BCAP) cnt = BCAP;
    for (int i = t; i < cnt; i += 256) sp[i] = packed[base + i];
    scnt[t] = 0;
    __syncthreads();
    for (int i = t; i < cnt; i += 256) atomicAdd(&scnt[sp[i] >> 24], 1u);
    __syncthreads();
    unsigned v = scnt[t];
    tsum[t] = v;
    __syncthreads();
    unsigned val = v;
    for (int d = 1; d < 256; d <<= 1) {
        unsigned add = (t >= d) ? tsum[t - d] : 0u;
        __syncthreads();
        val += add;
        tsum[t] = val;
        __syncthreads();
    }
    unsigned excl = val - v;
    scur[t] = excl;
    const int segs = (NR - b * BSEG < BSEG) ? (NR - b * BSEG) : BSEG;
    if (t < segs) off[b * BSEG + t] = base + excl;
    __syncthreads();
    for (int i = t; i < cnt; i += 256) {
        unsigned p = sp[i];
        unsigned pos = atomicAdd(&scur[p >> 24], 1u);
        ssrc[pos] = p & 0x00FFFFFFu;
    }
    __syncthreads();
    for (int i = t; i < cnt; i += 256) packed[base + i] = ssrc[i];
}

// ---------------- aggregation v6: single-tile softmax + 16-edge (4-load) branch-free gather ----------------
// wave per node; lane=(sub,fc). Inner iter: 4 independent dwordx2 loads = 16 edges in flight.
// Pad edges (e >= cnt) have p=0 and src=0 -> pad loads hit the cached h[0] line (~free).
template<bool L1>
__global__ __launch_bounds__(256) void aggregate6(
    const int* __restrict__ csr_src, const unsigned* __restrict__ off,
    const __half* __restrict__ h,    // [R, NN, 64] fp16
    const float* __restrict__ als, const float* __restrict__ ald,  // [R, NN]
    const float* __restrict__ bias,  // [R, 64]
    float* __restrict__ outp)        // [NN, 64]
{
    __shared__ float sbuf[4][64];    // fallback-path layout conversion only
    const int wid = threadIdx.x >> 6;
    const int node = blockIdx.x * 4 + wid;
    if (node >= NN) return;
    const int lane = threadIdx.x & 63;
    const int sub = lane >> 4;       // edge-in-quad 0..3
    const int fc = lane & 15;        // feature chunk 0..15 (4 features each)

    unsigned start[RRR]; int cnt[RRR]; float aldv[RRR];
    int maxcnt = 0;
#pragma unroll
    for (int r = 0; r < RRR; ++r) {
        int idx = r * NN + node;
        unsigned s = off[idx];
        unsigned e = (idx == NR - 1) ? (unsigned)((size_t)RRR * EE) : off[idx + 1];
        start[r] = s; cnt[r] = (int)(e - s); aldv[r] = ald[idx];
        if (cnt[r] > maxcnt) maxcnt = cnt[r];
    }

    float4 total = make_float4(0.f, 0.f, 0.f, 0.f);

    if (maxcnt <= 64) {
        // ---- fused single-tile path (max degree << 64 for this data) ----
        int srcv[RRR]; float lr[RRR];
#pragma unroll
        for (int r = 0; r < RRR; ++r) {
            bool act = lane < cnt[r];
            int s_ = act ? csr_src[start[r] + lane] : 0;      // coalesced; inactive lanes -> src 0
            srcv[r] = s_;
            float sv = act ? (als[r * NN + s_] + aldv[r]) : -3.0e38f;  // 4B gather, L2-resident
            lr[r] = (sv > 0.f) ? sv : SLOPE * sv;
        }
        float m[RRR];
#pragma unroll
        for (int r = 0; r < RRR; ++r) m[r] = lr[r];
#pragma unroll
        for (int o = 32; o; o >>= 1) {
#pragma unroll
            for (int r = 0; r < RRR; ++r) m[r] = fmaxf(m[r], __shfl_xor(m[r], o));
        }
        float p[RRR], den[RRR];
#pragma unroll
        for (int r = 0; r < RRR; ++r) {
            p[r] = (lane < cnt[r]) ? __expf(lr[r] - m[r]) : 0.f;   // p=0 for pad lanes
            den[r] = p[r];
        }
#pragma unroll
        for (int o = 32; o; o >>= 1) {
#pragma unroll
            for (int r = 0; r < RRR; ++r) den[r] += __shfl_xor(den[r], o);
        }
#pragma unroll
        for (int r = 0; r < RRR; ++r) {
            float inv = (cnt[r] > 0) ? 1.f / den[r] : 0.f;
            const __half* hr = h + (size_t)r * NN * DOUT;
            float4 acc = make_float4(0.f, 0.f, 0.f, 0.f);
            const int nq = (cnt[r] + 15) >> 4;     // 16-edge super-groups (1 for deg<=16: ~97%)
            for (int q = 0; q < nq; ++q) {
                const int base = q * 16;
                float pl[4]; int sl[4];
#pragma unroll
                for (int l = 0; l < 4; ++l) {      // broadcast 16 edges' (p, src)
                    int e = base + l * 4 + sub;    // e <= 63 always
                    pl[l] = __shfl(p[r], e);
                    sl[l] = __shfl(srcv[r], e);
                }
                uint2 rl[4];
#pragma unroll
                for (int l = 0; l < 4; ++l)        // 4 independent loads, pipelined
                    rl[l] = *(const uint2*)(hr + (size_t)sl[l] * DOUT + fc * 4);
#pragma unroll
                for (int l = 0; l < 4; ++l) {
                    float2 f01 = __half22float2(*(const __half2*)&rl[l].x);
                    float2 f23 = __half22float2(*(const __half2*)&rl[l].y);
                    acc.x = fmaf(pl[l], f01.x, acc.x);
                    acc.y = fmaf(pl[l], f01.y, acc.y);
                    acc.z = fmaf(pl[l], f23.x, acc.z);
                    acc.w = fmaf(pl[l], f23.y, acc.w);
                }
            }
            // reduce over the 4 sub-groups
            acc.x += __shfl_xor(acc.x, 16); acc.y += __shfl_xor(acc.y, 16);
            acc.z += __shfl_xor(acc.z, 16); acc.w += __shfl_xor(acc.w, 16);
            acc.x += __shfl_xor(acc.x, 32); acc.y += __shfl_xor(acc.y, 32);
            acc.z += __shfl_xor(acc.z, 32); acc.w += __shfl_xor(acc.w, 32);
            total.x = fmaf(acc.x, inv, total.x);
            total.y = fmaf(acc.y, inv, total.y);
            total.z = fmaf(acc.z, inv, total.z);
            total.w = fmaf(acc.w, inv, total.w);
        }
    } else {
        // ---- general fallback: online softmax, scalar broadcast (lane=feature) ----
        float totalS = 0.f;
#pragma unroll
        for (int r = 0; r < RRR; ++r) {
            if (cnt[r] <= 0) continue;
            const __half* hr = h + (size_t)r * NN * DOUT;
            const float* alsr = als + (size_t)r * NN;
            float m = -3.4e38f, den = 0.f, accv = 0.f;
            for (int t0 = 0; t0 < cnt[r]; t0 += 64) {
                int j = t0 + lane;
                bool act = (j < cnt[r]);
                int src = 0;
                float lrv = -3.4e38f;
                if (act) {
                    src = csr_src[start[r] + j];
                    float sv = alsr[src] + aldv[r];
                    lrv = (sv > 0.f) ? sv : SLOPE * sv;
                }
                float mt = lrv;
#pragma unroll
                for (int o = 32; o; o >>= 1) mt = fmaxf(mt, __shfl_xor(mt, o));
                float mnew = fmaxf(m, mt);
                float scale = __expf(m - mnew);
                den *= scale; accv *= scale; m = mnew;
                float p = act ? __expf(lrv - m) : 0.f;
                float ps = p;
#pragma unroll
                for (int o = 32; o; o >>= 1) ps += __shfl_xor(ps, o);
                den += ps;
                int tcnt = cnt[r] - t0; if (tcnt > 64) tcnt = 64;
                for (int j2 = 0; j2 < tcnt; ++j2) {
                    int sj = __builtin_amdgcn_readlane(src, j2);
                    float pj = __int_as_float(__builtin_amdgcn_readlane(__float_as_int(p), j2));
                    accv = fmaf(pj, __half2float(hr[(size_t)sj * DOUT + lane]), accv);
                }
            }
            totalS += accv / den;
        }
        sbuf[wid][lane] = totalS;     // wave-internal layout conversion
        __builtin_amdgcn_s_waitcnt(0);
        total = *(const float4*)&sbuf[wid][fc * 4];
    }

    // ---- epilogue in float4 layout (replicated across sub) ----
    float4 b4 = make_float4(0.f, 0.f, 0.f, 0.f);
#pragma unroll
    for (int r = 0; r < RRR; ++r) {
        float4 bb = *(const float4*)(bias + r * DOUT + fc * 4);
        b4.x += bb.x; b4.y += bb.y; b4.z += bb.z; b4.w += bb.w;
    }
    float4 v;
    v.x = (total.x + b4.x) * (1.f / 3.f);
    v.y = (total.y + b4.y) * (1.f / 3.f);
    v.z = (total.z + b4.z) * (1.f / 3.f);
    v.w = (total.w + b4.w) * (1.f / 3.f);
    if (L1) {
        float ss = v.x * v.x + v.y * v.y + v.z * v.z + v.w * v.w;
#pragma unroll
        for (int o = 8; o; o >>= 1) ss += __shfl_xor(ss, o);   // sum over 16 fc in sub-group
        float di = 1.f / fmaxf(sqrtf(ss), 1e-12f);
        v.x = fmaxf(v.x * di, 0.f);
        v.y = fmaxf(v.y * di, 0.f);
        v.z = fmaxf(v.z * di, 0.f);
        v.w = fmaxf(v.w * di, 0.f);
    }
    if (sub == 0) *(float4*)(outp + (size_t)node * DOUT + fc * 4) = v;  // 256B/node, coalesced
}

// ---------------- launch ----------------
extern "C" void kernel_launch(void* const* d_in, const int* in_sizes, int n_in,
                              void* d_out, int out_size, void* d_ws, size_t ws_size,
                              hipStream_t stream) {
    const float* x   = (const float*)d_in[0];
    const int* ei0   = (const int*)d_in[1];
    const int* ei1   = (const int*)d_in[2];
    const int* ei2   = (const int*)d_in[3];
    const float* W1  = (const float*)d_in[4];
    const float* as1 = (const float*)d_in[5];
    const float* ad1 = (const float*)d_in[6];
    const float* b1  = (const float*)d_in[7];
    const float* W2  = (const float*)d_in[8];
    const float* as2 = (const float*)d_in[9];
    const float* ad2 = (const float*)d_in[10];
    const float* b2  = (const float*)d_in[11];
    float* out = (float*)d_out;

    // workspace carve-up (4B units)
    float* ws = (float*)d_ws;
    size_t off_u = 0;
    __half* h       = (__half*)(ws + off_u); off_u += (size_t)RRR * NN * DOUT / 2;  // fp16: 9.6M floats
    float* als      = ws + off_u; off_u += (size_t)RRR * NN;
    float* ald      = ws + off_u; off_u += (size_t)RRR * NN;
    unsigned* packed= (unsigned*)(ws + off_u); off_u += (size_t)RRR * EE; // 3M; becomes csr_src
    unsigned* off   = (unsigned*)(ws + off_u); off_u += NR;
    float* Wt1      = ws + off_u; off_u += (size_t)RRR * DIN * DOUT;
    float* Wt2      = ws + off_u; off_u += (size_t)RRR * DOUT * DOUT;
    float* hmid     = ws + off_u;                                          // 6.4M floats
    unsigned* M     = (unsigned*)hmid;          // overlaps hmid: MT=432k < 6.4M; dead before layer 1
    unsigned* bsum  = M + MT;

    dim3 blk(256);
    dim3 gG2((NN + 63) / 64, RRR);    // 1563 x 3
    dim3 gC(NCH_PER_R, RRR);          // 123 x 3
    int gA = NN / 4;                  // 25000

    // ---- CSR build (deterministic, no global atomics; shared by both layers) ----
    chunk_hist<<<gC, blk, 0, stream>>>(ei0, ei1, ei2, M);
    scan_block<<<NSCB, blk, 0, stream>>>(M, bsum);
    scan_bsums<<<1, blk, 0, stream>>>(bsum);
    add_off<<<(MT + 255) / 256, blk, 0, stream>>>(M, bsum);
    chunk_scatter<<<gC, blk, 0, stream>>>(ei0, ei1, ei2, M, packed);
    bucket_build<<<NBUCK, blk, 0, stream>>>(packed, M, off);
    const int* csr_src = (const int*)packed;

    transpose_W<<<6, blk, 0, stream>>>(W1, W2, Wt1, Wt2);

    // ---- layer 1 ----
    gemm_att4<DIN><<<gG2, blk, 0, stream>>>(x, Wt1, as1, ad1, h, als, ald);
    aggregate6<true><<<gA, blk, 0, stream>>>(csr_src, off, h, als, ald, b1, hmid);

    // ---- layer 2 ----
    gemm_att4<DOUT><<<gG2, blk, 0, stream>>>(hmid, Wt2, as2, ad2, h, als, ald);
    aggregate6<false><<<gA, blk, 0, stream>>>(csr_src, off, h, als, ald, b2, out);
}

// Round 10
// 335.527 us; speedup vs baseline: 1.4129x; 1.3164x over previous
//
#include <hip/hip_runtime.h>
#include <hip/hip_bf16.h>
#include <hip/hip_fp16.h>
#include <math.h>

constexpr int NN = 100000;
constexpr int EE = 1000000;
constexpr int RRR = 3;
constexpr int DIN = 128;
constexpr int DOUT = 64;
constexpr float SLOPE = 0.2f;
constexpr int NR = RRR * NN;                    // 300000 segments (relation-major)
constexpr int BSEG = 256;                       // segments per bucket
constexpr int NBUCK = (NR + BSEG - 1) / BSEG;   // 1172
constexpr int BCAP = 4096;                      // max edges/bucket (mean 2560, sigma ~51)
constexpr int CHUNK_E = 8192;                   // edges per chunk-block
constexpr int NCH_PER_R = (EE + CHUNK_E - 1) / CHUNK_E;   // 123
constexpr int NCH = RRR * NCH_PER_R;            // 369
constexpr int MT = NBUCK * NCH;                 // 432468 matrix entries
constexpr int SCAN_CHUNK = 1024;
constexpr int NSCB = (MT + SCAN_CHUNK - 1) / SCAN_CHUNK;  // 423

using f16x8 = __attribute__((ext_vector_type(8))) _Float16;
using f32x4 = __attribute__((ext_vector_type(4))) float;

// ---------------- x -> fp16 cast ----------------
__global__ __launch_bounds__(256) void xcast(const float* __restrict__ x, __half* __restrict__ xh)
{
    int base = (blockIdx.x * 256 + threadIdx.x) * 4;
    if (base >= NN * DIN) return;
    float4 v = *(const float4*)(x + base);
    __half2* o = (__half2*)(xh + base);
    o[0] = __floats2half2_rn(v.x, v.y);
    o[1] = __floats2half2_rn(v.z, v.w);
}

// ---------------- W -> MFMA B-fragment pack (fp16) ----------------
// Wp[r][ks][nt][lane][j] = W[r][k = ks*32+(lane>>4)*8+j][c = nt*16+(lane&15)]
__global__ __launch_bounds__(256) void pack_W(
    const float* __restrict__ W1, const float* __restrict__ W2,
    __half* __restrict__ Wp1, __half* __restrict__ Wp2)
{
    int r = blockIdx.x;  // 0..2
    for (int i = threadIdx.x; i < 4 * 4 * 512; i += 256) {    // W1: KS=4
        int j = i & 7, lane = (i >> 3) & 63, nt = (i >> 9) & 3, ks = i >> 11;
        int k = ks * 32 + (lane >> 4) * 8 + j, c = nt * 16 + (lane & 15);
        Wp1[((size_t)r * 16 + ks * 4 + nt) * 512 + lane * 8 + j] = __float2half(W1[(r * DIN + k) * 64 + c]);
    }
    for (int i = threadIdx.x; i < 2 * 4 * 512; i += 256) {    // W2: KS=2
        int j = i & 7, lane = (i >> 3) & 63, nt = (i >> 9) & 3, ks = i >> 11;
        int k = ks * 32 + (lane >> 4) * 8 + j, c = nt * 16 + (lane & 15);
        Wp2[((size_t)r * 8 + ks * 4 + nt) * 512 + lane * 8 + j] = __float2half(W2[(r * DOUT + k) * 64 + c]);
    }
}

// ---------------- MFMA GEMM + attention logits ----------------
// block: 4 waves; wave w: rows row0+w*16..+15 (A frag), 4 N-tiles, K/32 steps.
// A: lane holds x[row=lane&15][k=(lane>>4)*8+j] (16B/lane from global fp16).
// B: prepacked per-lane-contiguous. Acc fp32; als/ald from acc via 16-lane reduce.
template<int K>
__global__ __launch_bounds__(256) void gemm_mfma(
    const __half* __restrict__ xh,   // [NN, K] fp16
    const __half* __restrict__ Wp,   // packed [R][K/32][4][512]
    const float* __restrict__ asrc, const float* __restrict__ adst,  // [R,64]
    __half* __restrict__ h,          // [R, NN, 64] fp16
    float* __restrict__ als, float* __restrict__ ald)                // [R, NN]
{
    constexpr int KS = K / 32;
    __shared__ float outb[64 * 65];
    const int t = threadIdx.x;
    const int lane = t & 63;
    const int w = t >> 6;
    const int r = blockIdx.y;
    const int row0 = blockIdx.x * 64;

    const int kgrp = lane >> 4;                  // 0..3
    const int l15 = lane & 15;
    int arow = row0 + w * 16 + l15; if (arow >= NN) arow = NN - 1;   // tail clamp (loads only)
    const __half* abase = xh + (size_t)arow * K + kgrp * 8;
    const __half* wbase = Wp + ((size_t)r * KS * 4) * 512 + lane * 8;

    f32x4 acc[4] = {};
#pragma unroll
    for (int ks = 0; ks < KS; ++ks) {
        f16x8 a = *(const f16x8*)(abase + ks * 32);
#pragma unroll
        for (int nt = 0; nt < 4; ++nt) {
            f16x8 b = *(const f16x8*)(wbase + (size_t)(ks * 4 + nt) * 512);
            acc[nt] = __builtin_amdgcn_mfma_f32_16x16x32_f16(a, b, acc[nt], 0, 0, 0);
        }
    }

    // als/ald: lane holds cols {l15+16*nt} of rows row0+w*16+kgrp*4+i
    {
        float ps[4] = {0.f, 0.f, 0.f, 0.f}, pd[4] = {0.f, 0.f, 0.f, 0.f};
#pragma unroll
        for (int nt = 0; nt < 4; ++nt) {
            int c = l15 + 16 * nt;
            float a_ = asrc[r * 64 + c], d_ = adst[r * 64 + c];
#pragma unroll
            for (int i = 0; i < 4; ++i) {
                ps[i] = fmaf(acc[nt][i], a_, ps[i]);
                pd[i] = fmaf(acc[nt][i], d_, pd[i]);
            }
        }
#pragma unroll
        for (int o = 8; o; o >>= 1) {
#pragma unroll
            for (int i = 0; i < 4; ++i) {
                ps[i] += __shfl_xor(ps[i], o);
                pd[i] += __shfl_xor(pd[i], o);
            }
        }
        if (l15 == 0) {
#pragma unroll
            for (int i = 0; i < 4; ++i) {
                int row = row0 + w * 16 + kgrp * 4 + i;
                if (row < NN) { als[r * NN + row] = ps[i]; ald[r * NN + row] = pd[i]; }
            }
        }
    }

    // stage C to LDS (D layout: row=(lane>>4)*4+i, col=l15+16nt), then coalesced fp16 write
#pragma unroll
    for (int nt = 0; nt < 4; ++nt)
#pragma unroll
        for (int i = 0; i < 4; ++i)
            outb[(w * 16 + kgrp * 4 + i) * 65 + l15 + 16 * nt] = acc[nt][i];
    __syncthreads();

    const int nrows = (NN - row0 < 64) ? (NN - row0) : 64;
    __half2* h2 = (__half2*)(h + ((size_t)r * NN + row0) * 64);
    for (int idx = t; idx < nrows * 32; idx += 256) {
        int row = idx >> 5, cc = idx & 31;
        h2[row * 32 + cc] = __floats2half2_rn(outb[row * 65 + cc * 2], outb[row * 65 + cc * 2 + 1]);
    }
}

// ---------------- CSR build: deterministic counting-sort, NO global atomics ----------------

__global__ __launch_bounds__(256) void chunk_hist(
    const int* __restrict__ ei0, const int* __restrict__ ei1, const int* __restrict__ ei2,
    unsigned* __restrict__ M)
{
    __shared__ unsigned hist[NBUCK];
    const int r = blockIdx.y, bx = blockIdx.x;
    const int* ei = (r == 0) ? ei0 : ((r == 1) ? ei1 : ei2);
    const int t = threadIdx.x;
    for (int i = t; i < NBUCK; i += 256) hist[i] = 0;
    __syncthreads();
    const int e0 = bx * CHUNK_E;
    const int e1 = (e0 + CHUNK_E < EE) ? e0 + CHUNK_E : EE;
    for (int e = e0 + t; e < e1; e += 256) {
        int idx = r * NN + ei[EE + e];
        atomicAdd(&hist[idx >> 8], 1u);
    }
    __syncthreads();
    const int c = r * NCH_PER_R + bx;
    for (int i = t; i < NBUCK; i += 256) M[(size_t)i * NCH + c] = hist[i];
}

__global__ __launch_bounds__(256) void scan_block(unsigned* __restrict__ data, unsigned* __restrict__ bsum)
{
    __shared__ unsigned tsum[256];
    const int base = blockIdx.x * SCAN_CHUNK;
    const int t = threadIdx.x;
    const int i0 = base + t * 4;
    unsigned v[4];
#pragma unroll
    for (int k = 0; k < 4; ++k) v[k] = (i0 + k < MT) ? data[i0 + k] : 0u;
    unsigned run = 0;
#pragma unroll
    for (int k = 0; k < 4; ++k) { unsigned x = v[k]; v[k] = run; run += x; }
    tsum[t] = run;
    __syncthreads();
    unsigned val = run;
    for (int d = 1; d < 256; d <<= 1) {
        unsigned add = (t >= d) ? tsum[t - d] : 0u;
        __syncthreads();
        val += add;
        tsum[t] = val;
        __syncthreads();
    }
    unsigned texcl = val - run;
    if (t == 255) bsum[blockIdx.x] = val;
#pragma unroll
    for (int k = 0; k < 4; ++k)
        if (i0 + k < MT) data[i0 + k] = texcl + v[k];
}

__global__ __launch_bounds__(256) void scan_bsums(unsigned* __restrict__ bsum)
{
    __shared__ unsigned s[NSCB];
    int t = threadIdx.x;
    for (int i = t; i < NSCB; i += 256) s[i] = bsum[i];
    __syncthreads();
    if (t == 0) {
        unsigned run = 0;
        for (int i = 0; i < NSCB; ++i) { unsigned x = s[i]; s[i] = run; run += x; }
    }
    __syncthreads();
    for (int i = t; i < NSCB; i += 256) bsum[i] = s[i];
}

__global__ __launch_bounds__(256) void add_off(unsigned* __restrict__ data, const unsigned* __restrict__ bsum)
{
    int i = blockIdx.x * 256 + threadIdx.x;
    if (i >= MT) return;
    data[i] += bsum[i / SCAN_CHUNK];
}

__global__ __launch_bounds__(256) void chunk_scatter(
    const int* __restrict__ ei0, const int* __restrict__ ei1, const int* __restrict__ ei2,
    const unsigned* __restrict__ Ms, unsigned* __restrict__ packed)
{
    __shared__ unsigned cur[NBUCK];
    const int r = blockIdx.y, bx = blockIdx.x;
    const int* ei = (r == 0) ? ei0 : ((r == 1) ? ei1 : ei2);
    const int t = threadIdx.x;
    const int c = r * NCH_PER_R + bx;
    for (int i = t; i < NBUCK; i += 256) cur[i] = Ms[(size_t)i * NCH + c];
    __syncthreads();
    const int e0 = bx * CHUNK_E;
    const int e1 = (e0 + CHUNK_E < EE) ? e0 + CHUNK_E : EE;
    for (int e = e0 + t; e < e1; e += 256) {
        int src = ei[e];
        int idx = r * NN + ei[EE + e];
        unsigned pos = atomicAdd(&cur[idx >> 8], 1u);
        packed[pos] = (unsigned)src | ((unsigned)(idx & 255) << 24);
    }
}

__global__ __launch_bounds__(256) void bucket_build(
    unsigned* __restrict__ packed,        // in: pairs; out: csr_src (same buffer)
    const unsigned* __restrict__ Ms,      // scanned matrix: Ms[b*NCH] = bucket base
    unsigned* __restrict__ off)           // [NR]
{
    __shared__ unsigned sp[BCAP];
    __shared__ unsigned ssrc[BCAP];
    __shared__ unsigned scnt[BSEG];
    __shared__ unsigned scur[BSEG];
    __shared__ unsigned tsum[BSEG];
    const int b = blockIdx.x;
    const int t = threadIdx.x;
    const unsigned base = Ms[(size_t)b * NCH];
    const unsigned next = (b + 1 < NBUCK) ? Ms[(size_t)(b + 1) * NCH] : (unsigned)((size_t)RRR * EE);
    int cnt = (int)(next - base);
    if (cnt > BCAP) cnt = BCAP;
    for (int i = t; i < cnt; i += 256) sp[i] = packed[base + i];
    scnt[t] = 0;
    __syncthreads();
    for (int i = t; i < cnt; i += 256) atomicAdd(&scnt[sp[i] >> 24], 1u);
    __syncthreads();
    unsigned v = scnt[t];
    tsum[t] = v;
    __syncthreads();
    unsigned val = v;
    for (int d = 1; d < 256; d <<= 1) {
        unsigned add = (t >= d) ? tsum[t - d] : 0u;
        __syncthreads();
        val += add;
        tsum[t] = val;
        __syncthreads();
    }
    unsigned excl = val - v;
    scur[t] = excl;
    const int segs = (NR - b * BSEG < BSEG) ? (NR - b * BSEG) : BSEG;
    if (t < segs) off[b * BSEG + t] = base + excl;
    __syncthreads();
    for (int i = t; i < cnt; i += 256) {
        unsigned p = sp[i];
        unsigned pos = atomicAdd(&scur[p >> 24], 1u);
        ssrc[pos] = p & 0x00FFFFFFu;
    }
    __syncthreads();
    for (int i = t; i < cnt; i += 256) packed[base + i] = ssrc[i];
}

// ---------------- aggregation v6: single-tile softmax + 16-edge (4-load) branch-free gather ----------------
// L1 writes fp16 (next GEMM input); L2 writes fp32 final output.
template<bool L1>
__global__ __launch_bounds__(256) void aggregate6(
    const int* __restrict__ csr_src, const unsigned* __restrict__ off,
    const __half* __restrict__ h,    // [R, NN, 64] fp16
    const float* __restrict__ als, const float* __restrict__ ald,  // [R, NN]
    const float* __restrict__ bias,  // [R, 64]
    float* __restrict__ outp,        // [NN, 64] fp32 (L2)
    __half* __restrict__ outH)       // [NN, 64] fp16 (L1)
{
    __shared__ float sbuf[4][64];    // fallback-path layout conversion only
    const int wid = threadIdx.x >> 6;
    const int node = blockIdx.x * 4 + wid;
    if (node >= NN) return;
    const int lane = threadIdx.x & 63;
    const int sub = lane >> 4;       // edge-in-quad 0..3
    const int fc = lane & 15;        // feature chunk 0..15 (4 features each)

    unsigned start[RRR]; int cnt[RRR]; float aldv[RRR];
    int maxcnt = 0;
#pragma unroll
    for (int r = 0; r < RRR; ++r) {
        int idx = r * NN + node;
        unsigned s = off[idx];
        unsigned e = (idx == NR - 1) ? (unsigned)((size_t)RRR * EE) : off[idx + 1];
        start[r] = s; cnt[r] = (int)(e - s); aldv[r] = ald[idx];
        if (cnt[r] > maxcnt) maxcnt = cnt[r];
    }

    float4 total = make_float4(0.f, 0.f, 0.f, 0.f);

    if (maxcnt <= 64) {
        // ---- fused single-tile path (max degree << 64 for this data) ----
        int srcv[RRR]; float lr[RRR];
#pragma unroll
        for (int r = 0; r < RRR; ++r) {
            bool act = lane < cnt[r];
            int s_ = act ? csr_src[start[r] + lane] : 0;      // coalesced; inactive lanes -> src 0
            srcv[r] = s_;
            float sv = act ? (als[r * NN + s_] + aldv[r]) : -3.0e38f;  // 4B gather, L2-resident
            lr[r] = (sv > 0.f) ? sv : SLOPE * sv;
        }
        float m[RRR];
#pragma unroll
        for (int r = 0; r < RRR; ++r) m[r] = lr[r];
#pragma unroll
        for (int o = 32; o; o >>= 1) {
#pragma unroll
            for (int r = 0; r < RRR; ++r) m[r] = fmaxf(m[r], __shfl_xor(m[r], o));
        }
        float p[RRR], den[RRR];
#pragma unroll
        for (int r = 0; r < RRR; ++r) {
            p[r] = (lane < cnt[r]) ? __expf(lr[r] - m[r]) : 0.f;   // p=0 for pad lanes
            den[r] = p[r];
        }
#pragma unroll
        for (int o = 32; o; o >>= 1) {
#pragma unroll
            for (int r = 0; r < RRR; ++r) den[r] += __shfl_xor(den[r], o);
        }
#pragma unroll
        for (int r = 0; r < RRR; ++r) {
            float inv = (cnt[r] > 0) ? 1.f / den[r] : 0.f;
            const __half* hr = h + (size_t)r * NN * DOUT;
            float4 acc = make_float4(0.f, 0.f, 0.f, 0.f);
            const int nq = (cnt[r] + 15) >> 4;     // 16-edge super-groups (1 for deg<=16: ~97%)
            for (int q = 0; q < nq; ++q) {
                const int base = q * 16;
                float pl[4]; int sl[4];
#pragma unroll
                for (int l = 0; l < 4; ++l) {      // broadcast 16 edges' (p, src)
                    int e = base + l * 4 + sub;    // e <= 63 always
                    pl[l] = __shfl(p[r], e);
                    sl[l] = __shfl(srcv[r], e);
                }
                uint2 rl[4];
#pragma unroll
                for (int l = 0; l < 4; ++l)        // 4 independent loads, pipelined
                    rl[l] = *(const uint2*)(hr + (size_t)sl[l] * DOUT + fc * 4);
#pragma unroll
                for (int l = 0; l < 4; ++l) {
                    float2 f01 = __half22float2(*(const __half2*)&rl[l].x);
                    float2 f23 = __half22float2(*(const __half2*)&rl[l].y);
                    acc.x = fmaf(pl[l], f01.x, acc.x);
                    acc.y = fmaf(pl[l], f01.y, acc.y);
                    acc.z = fmaf(pl[l], f23.x, acc.z);
                    acc.w = fmaf(pl[l], f23.y, acc.w);
                }
            }
            // reduce over the 4 sub-groups
            acc.x += __shfl_xor(acc.x, 16); acc.y += __shfl_xor(acc.y, 16);
            acc.z += __shfl_xor(acc.z, 16); acc.w += __shfl_xor(acc.w, 16);
            acc.x += __shfl_xor(acc.x, 32); acc.y += __shfl_xor(acc.y, 32);
            acc.z += __shfl_xor(acc.z, 32); acc.w += __shfl_xor(acc.w, 32);
            total.x = fmaf(acc.x, inv, total.x);
            total.y = fmaf(acc.y, inv, total.y);
            total.z = fmaf(acc.z, inv, total.z);
            total.w = fmaf(acc.w, inv, total.w);
        }
    } else {
        // ---- general fallback: online softmax, scalar broadcast (lane=feature) ----
        float totalS = 0.f;
#pragma unroll
        for (int r = 0; r < RRR; ++r) {
            if (cnt[r] <= 0) continue;
            const __half* hr = h + (size_t)r * NN * DOUT;
            const float* alsr = als + (size_t)r * NN;
            float m = -3.4e38f, den = 0.f, accv = 0.f;
            for (int t0 = 0; t0 < cnt[r]; t0 += 64) {
                int j = t0 + lane;
                bool act = (j < cnt[r]);
                int src = 0;
                float lrv = -3.4e38f;
                if (act) {
                    src = csr_src[start[r] + j];
                    float sv = alsr[src] + aldv[r];
                    lrv = (sv > 0.f) ? sv : SLOPE * sv;
                }
                float mt = lrv;
#pragma unroll
                for (int o = 32; o; o >>= 1) mt = fmaxf(mt, __shfl_xor(mt, o));
                float mnew = fmaxf(m, mt);
                float scale = __expf(m - mnew);
                den *= scale; accv *= scale; m = mnew;
                float p = act ? __expf(lrv - m) : 0.f;
                float ps = p;
#pragma unroll
                for (int o = 32; o; o >>= 1) ps += __shfl_xor(ps, o);
                den += ps;
                int tcnt = cnt[r] - t0; if (tcnt > 64) tcnt = 64;
                for (int j2 = 0; j2 < tcnt; ++j2) {
                    int sj = __builtin_amdgcn_readlane(src, j2);
                    float pj = __int_as_float(__builtin_amdgcn_readlane(__float_as_int(p), j2));
                    accv = fmaf(pj, __half2float(hr[(size_t)sj * DOUT + lane]), accv);
                }
            }
            totalS += accv / den;
        }
        sbuf[wid][lane] = totalS;     // wave-internal layout conversion
        __builtin_amdgcn_s_waitcnt(0);
        total = *(const float4*)&sbuf[wid][fc * 4];
    }

    // ---- epilogue in float4 layout (replicated across sub) ----
    float4 b4 = make_float4(0.f, 0.f, 0.f, 0.f);
#pragma unroll
    for (int r = 0; r < RRR; ++r) {
        float4 bb = *(const float4*)(bias + r * DOUT + fc * 4);
        b4.x += bb.x; b4.y += bb.y; b4.z += bb.z; b4.w += bb.w;
    }
    float4 v;
    v.x = (total.x + b4.x) * (1.f / 3.f);
    v.y = (total.y + b4.y) * (1.f / 3.f);
    v.z = (total.z + b4.z) * (1.f / 3.f);
    v.w = (total.w + b4.w) * (1.f / 3.f);
    if (L1) {
        float ss = v.x * v.x + v.y * v.y + v.z * v.z + v.w * v.w;
#pragma unroll
        for (int o = 8; o; o >>= 1) ss += __shfl_xor(ss, o);   // sum over 16 fc in sub-group
        float di = 1.f / fmaxf(sqrtf(ss), 1e-12f);
        v.x = fmaxf(v.x * di, 0.f);
        v.y = fmaxf(v.y * di, 0.f);
        v.z = fmaxf(v.z * di, 0.f);
        v.w = fmaxf(v.w * di, 0.f);
        if (sub == 0) {
            __half2* o2 = (__half2*)(outH + (size_t)node * DOUT + fc * 4);
            o2[0] = __floats2half2_rn(v.x, v.y);
            o2[1] = __floats2half2_rn(v.z, v.w);
        }
    } else {
        if (sub == 0) *(float4*)(outp + (size_t)node * DOUT + fc * 4) = v;  // 256B/node, coalesced
    }
}

// ---------------- launch ----------------
extern "C" void kernel_launch(void* const* d_in, const int* in_sizes, int n_in,
                              void* d_out, int out_size, void* d_ws, size_t ws_size,
                              hipStream_t stream) {
    const float* x   = (const float*)d_in[0];
    const int* ei0   = (const int*)d_in[1];
    const int* ei1   = (const int*)d_in[2];
    const int* ei2   = (const int*)d_in[3];
    const float* W1  = (const float*)d_in[4];
    const float* as1 = (const float*)d_in[5];
    const float* ad1 = (const float*)d_in[6];
    const float* b1  = (const float*)d_in[7];
    const float* W2  = (const float*)d_in[8];
    const float* as2 = (const float*)d_in[9];
    const float* ad2 = (const float*)d_in[10];
    const float* b2  = (const float*)d_in[11];
    float* out = (float*)d_out;

    // workspace carve-up (4B units), ~90 MB total
    float* ws = (float*)d_ws;
    size_t off_u = 0;
    __half* h       = (__half*)(ws + off_u); off_u += (size_t)RRR * NN * DOUT / 2;  // 9.6M floats
    float* als      = ws + off_u; off_u += (size_t)RRR * NN;
    float* ald      = ws + off_u; off_u += (size_t)RRR * NN;
    unsigned* packed= (unsigned*)(ws + off_u); off_u += (size_t)RRR * EE; // 3M; becomes csr_src
    unsigned* off   = (unsigned*)(ws + off_u); off_u += NR;
    __half* xh      = (__half*)(ws + off_u); off_u += (size_t)NN * DIN / 2;   // 6.4M floats
    __half* hmid_h  = (__half*)(ws + off_u); off_u += (size_t)NN * DOUT / 2;  // 1.6M floats
    __half* Wp1     = (__half*)(ws + off_u); off_u += (3 * 16 * 512) / 2;
    __half* Wp2     = (__half*)(ws + off_u); off_u += (3 * 8 * 512) / 2;
    unsigned* M     = (unsigned*)(ws + off_u); off_u += MT;
    unsigned* bsum  = (unsigned*)(ws + off_u); off_u += NSCB + 8;

    dim3 blk(256);
    dim3 gG((NN + 63) / 64, RRR);     // 1563 x 3
    dim3 gC(NCH_PER_R, RRR);          // 123 x 3
    int gA = NN / 4;                  // 25000

    // ---- CSR build (deterministic, no global atomics; shared by both layers) ----
    chunk_hist<<<gC, blk, 0, stream>>>(ei0, ei1, ei2, M);
    scan_block<<<NSCB, blk, 0, stream>>>(M, bsum);
    scan_bsums<<<1, blk, 0, stream>>>(bsum);
    add_off<<<(MT + 255) / 256, blk, 0, stream>>>(M, bsum);
    chunk_scatter<<<gC, blk, 0, stream>>>(ei0, ei1, ei2, M, packed);
    bucket_build<<<NBUCK, blk, 0, stream>>>(packed, M, off);
    const int* csr_src = (const int*)packed;

    xcast<<<(NN * DIN / 4 + 255) / 256, blk, 0, stream>>>(x, xh);
    pack_W<<<3, blk, 0, stream>>>(W1, W2, Wp1, Wp2);

    // ---- layer 1 ----
    gemm_mfma<DIN><<<gG, blk, 0, stream>>>(xh, Wp1, as1, ad1, h, als, ald);
    aggregate6<true><<<gA, blk, 0, stream>>>(csr_src, off, h, als, ald, b1, out, hmid_h);

    // ---- layer 2 ----
    gemm_mfma<DOUT><<<gG, blk, 0, stream>>>(hmid_h, Wp2, as2, ad2, h, als, ald);
    aggregate6<false><<<gA, blk, 0, stream>>>(csr_src, off, h, als, ald, b2, out, hmid_h);
}